// Round 12
// baseline (45573.672 us; speedup 1.0000x reference)
//
#include <hip/hip_runtime.h>
#include <cstdint>

#define TT 256
#define HH 256
#define LL 3
#define NTH 512
#define SWG 16          // members per cluster
#define CLN 16          // clusters (8 rows each)
#define RW 8            // rows per cluster
#define LN_EPS 1e-5f
#define ACTSTRIDE 43008 // floats per cluster: gatesB 8192 + a1B 128 + r2P 32768
#define PL 516          // P4 plane stride (512 entries + pad), float4s

// ---------------- helpers ----------------

__device__ __forceinline__ float fast_sigmoid(float x) {
    return 1.f / (1.f + __expf(-x));
}
__device__ __forceinline__ float fast_tanh(float x) {
    float xc = fminf(fmaxf(x, -15.f), 15.f);
    float e = __expf(2.f * xc);
    return 1.f - 2.f / (e + 1.f);
}
__device__ __forceinline__ float relu(float x) { return fmaxf(x, 0.f); }

// LLC-coherent scalar access.
__device__ __forceinline__ void cst(float* p, float v) {
    __hip_atomic_store(p, v, __ATOMIC_RELAXED, __HIP_MEMORY_SCOPE_AGENT);
}
__device__ __forceinline__ float cld(const float* p) {
    return __hip_atomic_load(p, __ATOMIC_RELAXED, __HIP_MEMORY_SCOPE_AGENT);
}

// Fused reductions. Thread (n=tid&255, p=tid>>8) owns rows p*4..p*4+3.
// Waves 0-3 hold p=0 values, waves 4-7 p=1. All indices compile-time.
__device__ __forceinline__ void rowsum8(float v[8], float* scr, int tid) {
#pragma unroll
    for (int o = 32; o > 0; o >>= 1)
#pragma unroll
        for (int i = 0; i < 8; i++) v[i] += __shfl_down(v[i], o);
    int w = tid >> 6;
    if ((tid & 63) == 0)
#pragma unroll
        for (int i = 0; i < 8; i++) scr[w*8 + i] = v[i];
    __syncthreads();
    int b0 = (tid >> 8) * 4;
    float s[8];
#pragma unroll
    for (int i = 0; i < 8; i++) s[i] = 0.f;
#pragma unroll
    for (int k = 0; k < 4; k++)
#pragma unroll
        for (int i = 0; i < 8; i++) s[i] += scr[(b0 + k)*8 + i];
    __syncthreads();
#pragma unroll
    for (int i = 0; i < 8; i++) v[i] = s[i];
}

__device__ __forceinline__ void rowsum16(float v[16], float* scr, int tid) {
#pragma unroll
    for (int o = 32; o > 0; o >>= 1)
#pragma unroll
        for (int i = 0; i < 16; i++) v[i] += __shfl_down(v[i], o);
    int w = tid >> 6;
    if ((tid & 63) == 0)
#pragma unroll
        for (int i = 0; i < 16; i++) scr[w*16 + i] = v[i];
    __syncthreads();
    int b0 = (tid >> 8) * 4;
    float s[16];
#pragma unroll
    for (int i = 0; i < 16; i++) s[i] = 0.f;
#pragma unroll
    for (int k = 0; k < 4; k++)
#pragma unroll
        for (int i = 0; i < 16; i++) s[i] += scr[(b0 + k)*16 + i];
    __syncthreads();
#pragma unroll
    for (int i = 0; i < 16; i++) v[i] = s[i];
}

// 8-row FMA: one weight f4 feeds 8 rows (32 FLOP / 16B load).
__device__ __forceinline__ void fma32(float4 w, float4 xlo, float4 xhi, float4* a) {
#pragma unroll
    for (int i = 0; i < 4; i++) {
        float xv = ((const float*)&xlo)[i];
        a[i].x = fmaf(w.x, xv, a[i].x); a[i].y = fmaf(w.y, xv, a[i].y);
        a[i].z = fmaf(w.z, xv, a[i].z); a[i].w = fmaf(w.w, xv, a[i].w);
    }
#pragma unroll
    for (int i = 0; i < 4; i++) {
        float xv = ((const float*)&xhi)[i];
        a[4+i].x = fmaf(w.x, xv, a[4+i].x); a[4+i].y = fmaf(w.y, xv, a[4+i].y);
        a[4+i].z = fmaf(w.z, xv, a[4+i].z); a[4+i].w = fmaf(w.w, xv, a[4+i].w);
    }
}

// ---------------- main kernel ----------------

struct Args {
    const float *params, *disp;
    const float *embed_b, *embed_g, *embed_beta;
    const float *skip_b;
    const float *gates_b;
    const float *inln_g, *inln_b, *hln_g, *hln_b, *sln_g, *sln_b;
    const float *ab1, *aw2, *ab2;
    const float *rb1, *rb2, *rln_g, *rln_b;
    const float *ob1, *oln_g, *oln_b, *ow2, *ob2;
    const float *gw, *a1w, *r1w, *r2w, *ew, *sw, *o1w;
    float* out;
    float* act;   // cluster activation buffers (accessed ONLY via cst/cld)
    int* bar;     // per-cluster sum counter, 128-int stride
};

// 512 threads, 8 rows/cluster, 16 members. Grid = 256 WGs = 1/CU exactly
// (LDS 113KB forces 1 WG/CU; residency guaranteed at any VGPR<=256 -> the
// cluster barrier cannot deadlock). fma32 doubles weight reuse vs R5's
// fma16: MV loads/thread halve, per-XCD weight stream halves.
__global__ __launch_bounds__(NTH) void xlstm_kernel(Args A) {
    const int tid = threadIdx.x;
    const int cid = blockIdx.x & 15;   // cluster; members share XCD (blockIdx%8==cid%8)
    const int m   = blockIdx.x >> 4;   // member 0..15
    const int n   = tid & 255;
    const int p   = tid >> 8;          // 0/1 -> rows p*4..p*4+3

    float* gatesB = A.act + (size_t)cid * ACTSTRIDE;   // [8][1024]
    float* a1B  = gatesB + 8192;                       // [16][8] imp partials
    float* r2P  = gatesB + 8320;                       // [16][8][256] r2 partials
    int* cnt = A.bar + cid * 128;                      // cluster sum counter

    __shared__ __align__(16) float4 P4[8 * PL];   // 66 KB partials
    __shared__ __align__(16) float xnhnT[512][8];
    __shared__ __align__(16) float cT[256][8];
    __shared__ __align__(16) float hT[256][8];
    __shared__ __align__(16) float xT[256][8];
    __shared__ __align__(16) float skT[128][8];
    __shared__ __align__(16) float r1locT[32][8]; // member's r1 slice (local k)
    __shared__ float xtT[17 * 8];
    __shared__ float scr[128];

    float x1[4] = {0.f, 0.f, 0.f, 0.f};
    float h1[LL][4] = {};
    float c1[LL][4] = {};

    int ep = 0;
    auto csig = [&]() {
        ep++;
        __syncthreads();   // all WG cst stores drained to LLC
        if (tid == 0)
            __hip_atomic_fetch_add(cnt, 1, __ATOMIC_RELAXED, __HIP_MEMORY_SCOPE_AGENT);
    };
    auto cwait = [&]() {
        if (tid == 0) {
            while (__hip_atomic_load(cnt, __ATOMIC_RELAXED, __HIP_MEMORY_SCOPE_AGENT) < SWG * ep)
                __builtin_amdgcn_s_sleep(4);
            asm volatile("" ::: "memory");
        }
        __syncthreads();
    };

    if (tid < 128) {
        int kk = tid >> 3, rr = tid & 7;
        xtT[(1 + kk) * 8 + rr] = A.params[(RW * cid + rr) * 16 + kk];
    }
    if (tid < 8) xtT[tid] = A.disp[(RW * cid + tid) * TT + 0];
    __syncthreads();

    for (int t = 0; t < TT; t++) {
        // ---- embed + skip (redundant); xtT primed by prev step ----
        float e[4];
#pragma unroll
        for (int i = 0; i < 4; i++) e[i] = A.embed_b[n];
#pragma unroll 4
        for (int k = 0; k < 17; k++) {
            float w = A.ew[k * 256 + n];
#pragma unroll
            for (int i = 0; i < 4; i++) e[i] = fmaf(w, xtT[k*8 + p*4 + i], e[i]);
        }
        {
            int mm = tid & 127, q2 = tid >> 7;   // rows q2, q2+4
            float s0 = A.skip_b[mm], s1 = s0;
#pragma unroll 4
            for (int k = 0; k < 17; k++) {
                float w = A.sw[k * 128 + mm];
                s0 = fmaf(w, xtT[k*8 + q2], s0);
                s1 = fmaf(w, xtT[k*8 + q2 + 4], s1);
            }
            skT[mm][q2] = relu(s0); skT[mm][q2 + 4] = relu(s1);
        }
        {
            float v[8];
#pragma unroll
            for (int i = 0; i < 4; i++) { v[2*i] = e[i]; v[2*i+1] = e[i]*e[i]; }
            rowsum8(v, scr, tid);
#pragma unroll
            for (int i = 0; i < 4; i++) {
                float mu = v[2*i]*(1.f/HH);
                float inv = rsqrtf(v[2*i+1]*(1.f/HH) - mu*mu + LN_EPS);
                x1[i] = relu((e[i] - mu)*inv*A.embed_g[n] + A.embed_beta[n]);
            }
        }

#pragma unroll 1
        for (int l = 0; l < LL; l++) {
            // ---- phase A (redundant): fused xn+hn LN, stage cT ----
            {
                float v[16];
#pragma unroll
                for (int i = 0; i < 4; i++) {
                    v[2*i] = x1[i]; v[2*i+1] = x1[i]*x1[i];
                    float hh = h1[l][i];
                    v[8+2*i] = hh; v[9+2*i] = hh*hh;
                }
                rowsum16(v, scr, tid);
                const float* g  = A.inln_g + l*HH; const float* b  = A.inln_b + l*HH;
                const float* g2 = A.hln_g  + l*HH; const float* b2 = A.hln_b  + l*HH;
                float4 xw, hw, cw;
#pragma unroll
                for (int i = 0; i < 4; i++) {
                    float mu = v[2*i]*(1.f/HH);
                    float inv = rsqrtf(v[2*i+1]*(1.f/HH) - mu*mu + LN_EPS);
                    ((float*)&xw)[i] = (x1[i] - mu)*inv*g[n] + b[n];
                    mu = v[8+2*i]*(1.f/HH);
                    inv = rsqrtf(v[9+2*i]*(1.f/HH) - mu*mu + LN_EPS);
                    ((float*)&hw)[i] = (h1[l][i] - mu)*inv*g2[n] + b2[n];
                    ((float*)&cw)[i] = c1[l][i];
                }
                *(float4*)&xnhnT[n][p*4]       = xw;
                *(float4*)&xnhnT[256 + n][p*4] = hw;
                *(float4*)&cT[n][p*4]          = cw;
            }
            __syncthreads();

            // ---- MV1: gates N-slice (64 cols=16 f4). 32 kgs x 16 k ----
            {
                int j = tid & 15, kg = tid >> 4;
                const float4* Wq = (const float4*)A.gw + (size_t)l*512*256 + (m*16 + j);
                float4 a[8];
#pragma unroll
                for (int i = 0; i < 8; i++) a[i] = make_float4(0,0,0,0);
                int k0 = kg * 16;
#pragma unroll 8
                for (int kk = 0; kk < 16; kk++) {
                    int k = k0 + kk;
                    fma32(Wq[(size_t)k * 256],
                          *(const float4*)&xnhnT[k][0],
                          *(const float4*)&xnhnT[k][4], a);
                }
                int b = kg*16 + j;
#pragma unroll
                for (int i = 0; i < 8; i++) P4[i*PL + b] = a[i];
            }
            __syncthreads();
            if (tid < 128) {
                int j2 = tid >> 3, row = tid & 7;
                float4 s = {0,0,0,0};
#pragma unroll
                for (int kg = 0; kg < 32; kg++) {
                    float4 v4 = P4[row*PL + kg*16 + j2];
                    s.x += v4.x; s.y += v4.y; s.z += v4.z; s.w += v4.w;
                }
                float* d = gatesB + row*1024 + m*64 + j2*4;
                cst(d+0, s.x); cst(d+1, s.y); cst(d+2, s.z); cst(d+3, s.w);
            }
            __syncthreads();
            // ---- MV1b: a1 N-slice (16 cols=4 f4). 32 kgs x 8 k, 128 thr ----
            if (tid < 128) {
                int j = tid & 3, kg = tid >> 2;
                const float4* Wq = (const float4*)A.a1w + (size_t)l*256*64 + (m*4 + j);
                float4 a[8];
#pragma unroll
                for (int i = 0; i < 8; i++) a[i] = make_float4(0,0,0,0);
                int k0 = kg * 8;
#pragma unroll
                for (int kk = 0; kk < 8; kk++) {
                    int k = k0 + kk;
                    fma32(Wq[(size_t)k * 64],
                          *(const float4*)&cT[k][0],
                          *(const float4*)&cT[k][4], a);
                }
                int b = kg*4 + j;
#pragma unroll
                for (int i = 0; i < 8; i++) P4[i*PL + b] = a[i];
            }
            __syncthreads();
            if (tid < 32) {
                int j2 = tid >> 3, row = tid & 7;
                float4 s = {0,0,0,0};
#pragma unroll
                for (int kg = 0; kg < 32; kg++) {
                    float4 v4 = P4[row*PL + kg*4 + j2];
                    s.x += v4.x; s.y += v4.y; s.z += v4.z; s.w += v4.w;
                }
                const float* ab1p = A.ab1 + l*HH + m*16 + j2*4;
                const float* aw2p = A.aw2 + l*HH + m*16 + j2*4;
                float d = fast_tanh(s.x + ab1p[0]) * aw2p[0]
                        + fast_tanh(s.y + ab1p[1]) * aw2p[1]
                        + fast_tanh(s.z + ab1p[2]) * aw2p[2]
                        + fast_tanh(s.w + ab1p[3]) * aw2p[3];
                scr[j2*8 + row] = d;
            }
            __syncthreads();
            if (tid < 8) {
                float s = 0.f;
#pragma unroll
                for (int j2 = 0; j2 < 4; j2++) s += scr[j2*8 + tid];
                cst(a1B + m*8 + tid, s);
            }

            // ---- B1; r1w/r2w prefetch hidden under the wait (R5-proven) ----
            float4 w2[4], w3[4];
            csig();
            {
                int j = tid & 7, kg = tid >> 3, k0 = kg * 4;       // 64 kgs
                const float4* Wq2 = (const float4*)A.r1w + (size_t)l*256*128 + (m*8 + j);
#pragma unroll
                for (int kk = 0; kk < 4; kk++) w2[kk] = Wq2[(size_t)(k0 + kk) * 128];
                int j3 = tid & 63, kg3 = tid >> 6, k03 = kg3 * 4;  // 8 kgs
                const float4* Wq3 = (const float4*)A.r2w + (size_t)l*512*64
                                    + (size_t)(m*32) * 64 + j3;
#pragma unroll
                for (int kk = 0; kk < 4; kk++) w3[kk] = Wq3[(size_t)(k03 + kk) * 64];
            }
            cwait();   // B1: gates + a1 partials visible

            // ---- phase B (redundant): imp, c, h ----
            float imp[4];
#pragma unroll
            for (int i = 0; i < 4; i++) {
                int ri = p*4 + i;
                float sA = A.ab2[l];
#pragma unroll
                for (int mm = 0; mm < SWG; mm++) sA += cld(a1B + mm*8 + ri);
                imp[i] = fast_sigmoid(sA);
            }
            const float* gb = A.gates_b + l*1024;
            float craw[4], og[4];
#pragma unroll
            for (int i = 0; i < 4; i++) {
                int ri = p*4 + i;
                const float* go = gatesB + ri*1024;
                float ii = fast_sigmoid(cld(go + n) + gb[n]);
                float ff = fast_sigmoid(cld(go + 256 + n) + gb[256+n]);
                float gg = fast_tanh(cld(go + 512 + n) + gb[512+n]);
                og[i] = fast_sigmoid(cld(go + 768 + n) + gb[768+n]);
                craw[i] = (ff * c1[l][i] + ii * gg) * imp[i];
            }
            {
                float v[8];
#pragma unroll
                for (int i = 0; i < 4; i++) { v[2*i] = craw[i]; v[2*i+1] = craw[i]*craw[i]; }
                rowsum8(v, scr, tid);
                const float* g = A.sln_g + l*HH; const float* b = A.sln_b + l*HH;
                float4 hw;
#pragma unroll
                for (int i = 0; i < 4; i++) {
                    float mu = v[2*i]*(1.f/HH);
                    float inv = rsqrtf(v[2*i+1]*(1.f/HH) - mu*mu + LN_EPS);
                    float cn = (craw[i] - mu)*inv*g[n] + b[n];
                    c1[l][i] = cn;
                    float hh = og[i] * fast_tanh(cn);
                    h1[l][i] = hh;
                    ((float*)&hw)[i] = hh;
                }
                *(float4*)&hT[n][p*4] = hw;
            }
            __syncthreads();

            // ---- MV2: r1 N-slice (32 cols=8 f4). 64 kgs x 4 k, prefetched ----
            {
                int j = tid & 7, kg = tid >> 3;
                float4 a[8];
#pragma unroll
                for (int i = 0; i < 8; i++) a[i] = make_float4(0,0,0,0);
                int k0 = kg * 4;
#pragma unroll
                for (int kk = 0; kk < 4; kk++) {
                    int k = k0 + kk;
                    fma32(w2[kk], *(const float4*)&hT[k][0],
                                  *(const float4*)&hT[k][4], a);
                }
                int b = kg*8 + j;
#pragma unroll
                for (int i = 0; i < 8; i++) P4[i*PL + b] = a[i];
            }
            __syncthreads();
            if (tid < 64) {
                int j2 = tid >> 3, row = tid & 7;
                float4 s = {0,0,0,0};
#pragma unroll
                for (int kg = 0; kg < 64; kg++) {
                    float4 v4 = P4[row*PL + kg*8 + j2];
                    s.x += v4.x; s.y += v4.y; s.z += v4.z; s.w += v4.w;
                }
                const float* rb1p = A.rb1 + l*512 + m*32 + j2*4;
                r1locT[j2*4 + 0][row] = relu(s.x + rb1p[0]);
                r1locT[j2*4 + 1][row] = relu(s.y + rb1p[1]);
                r1locT[j2*4 + 2][row] = relu(s.z + rb1p[2]);
                r1locT[j2*4 + 3][row] = relu(s.w + rb1p[3]);
            }
            __syncthreads();

            // ---- MV3: r2 K-slice (32 k-rows, all 64 f4 cols). 8 kgs x 4 k ----
            {
                int j = tid & 63, kg = tid >> 6;
                float4 a[8];
#pragma unroll
                for (int i = 0; i < 8; i++) a[i] = make_float4(0,0,0,0);
                int k0 = kg * 4;
#pragma unroll
                for (int kk = 0; kk < 4; kk++) {
                    int lk = k0 + kk;
                    fma32(w3[kk], *(const float4*)&r1locT[lk][0],
                                  *(const float4*)&r1locT[lk][4], a);
                }
                int b = kg*64 + j;
#pragma unroll
                for (int i = 0; i < 8; i++) P4[i*PL + b] = a[i];
            }
            __syncthreads();
            {
                int j2 = tid >> 3, row = tid & 7;
                float4 s = {0,0,0,0};
#pragma unroll
                for (int kg = 0; kg < 8; kg++) {
                    float4 v4 = P4[row*PL + kg*64 + j2];
                    s.x += v4.x; s.y += v4.y; s.z += v4.z; s.w += v4.w;
                }
                float* d = r2P + m*2048 + row*256 + j2*4;
                cst(d+0, s.x); cst(d+1, s.y); cst(d+2, s.z); cst(d+3, s.w);
            }
            csig(); cwait();   // B2: r2 partials visible

            // ---- phase C (redundant): x = LN(sum r2 + rb2 + h) + res ----
            const float* rb2p = A.rb2 + l*HH;
            float sarr[4];
#pragma unroll
            for (int i = 0; i < 4; i++) {
                int ri = p*4 + i;
                float s0 = rb2p[n] + h1[l][i];
#pragma unroll
                for (int mm = 0; mm < SWG; mm++)
                    s0 += cld(r2P + mm*2048 + ri*256 + n);
                sarr[i] = s0;
            }
            {
                float v[8];
#pragma unroll
                for (int i = 0; i < 4; i++) { v[2*i] = sarr[i]; v[2*i+1] = sarr[i]*sarr[i]; }
                rowsum8(v, scr, tid);
                const float* g = A.rln_g + l*HH; const float* b = A.rln_b + l*HH;
#pragma unroll
                for (int i = 0; i < 4; i++) {
                    float mu = v[2*i]*(1.f/HH);
                    float inv = rsqrtf(v[2*i+1]*(1.f/HH) - mu*mu + LN_EPS);
                    x1[i] = (sarr[i] - mu)*inv*g[n] + b[n] + x1[i];
                }
            }
        }   // layers

        // ---- head: split-redundant, no cluster barrier. Members 0-7 do
        // rows 0-3, members 8-15 rows 4-7 (all replicated locally); only
        // m==0 / m==8 write out. Same per-member cost as R5's head.
        {
            float4 xw;
#pragma unroll
            for (int i = 0; i < 4; i++) ((float*)&xw)[i] = x1[i];
            *(float4*)&xT[n][p*4] = xw;
        }
        if (tid < 8 && t < TT - 1)
            xtT[tid] = A.disp[(RW * cid + tid) * TT + t + 1];   // prime next step
        __syncthreads();
        {
            int half = m >> 3;
            int j = tid & 31, z = tid >> 5;       // z 0..15
            int row4 = z & 3, kg = z >> 2;        // kg 0..3 x 96 k
            int grow = half*4 + row4;
            const float4* W4 = (const float4*)A.o1w;
            float4 a4 = {0,0,0,0};
            int k0 = kg * 96;
#pragma unroll 8
            for (int kk = 0; kk < 96; kk++) {
                int k = k0 + kk;
                float xv = (k < 256) ? xT[k][grow] : skT[k - 256][grow];
                float4 w = W4[(size_t)k * 32 + j];
                a4.x = fmaf(w.x, xv, a4.x); a4.y = fmaf(w.y, xv, a4.y);
                a4.z = fmaf(w.z, xv, a4.z); a4.w = fmaf(w.w, xv, a4.w);
            }
            P4[z * 33 + j] = a4;
        }
        __syncthreads();
        if (tid < 128) {
            int j = tid & 31, row4 = tid >> 5;
            int half = m >> 3, grow = half*4 + row4;
            float4 v4 = {0,0,0,0};
#pragma unroll
            for (int kg = 0; kg < 4; kg++) {
                float4 pv = P4[(kg * 4 + row4) * 33 + j];
                v4.x += pv.x; v4.y += pv.y; v4.z += pv.z; v4.w += pv.w;
            }
            float4 b1 = ((const float4*)A.ob1)[j];
            v4.x += b1.x; v4.y += b1.y; v4.z += b1.z; v4.w += b1.w;
            float s = v4.x + v4.y + v4.z + v4.w;
            float q = v4.x*v4.x + v4.y*v4.y + v4.z*v4.z + v4.w*v4.w;
#pragma unroll
            for (int o = 16; o > 0; o >>= 1) { s += __shfl_down(s, o); q += __shfl_down(q, o); }
            s = __shfl(s, tid & 32);
            q = __shfl(q, tid & 32);
            float mu = s * (1.f/128.f);
            float inv = rsqrtf(q * (1.f/128.f) - mu*mu + LN_EPS);
            float4 g4 = ((const float4*)A.oln_g)[j];
            float4 be4 = ((const float4*)A.oln_b)[j];
            float4 w24 = ((const float4*)A.ow2)[j];
            float part = relu((v4.x - mu) * inv * g4.x + be4.x) * w24.x
                       + relu((v4.y - mu) * inv * g4.y + be4.y) * w24.y
                       + relu((v4.z - mu) * inv * g4.z + be4.z) * w24.z
                       + relu((v4.w - mu) * inv * g4.w + be4.w) * w24.w;
#pragma unroll
            for (int o = 16; o > 0; o >>= 1) part += __shfl_down(part, o);
            if ((m & 7) == 0 && (tid & 31) == 0)
                A.out[(RW*cid + grow) * TT + t] = part + A.ob2[0];
        }
        __syncthreads();   // protect LDS for next step
    }
}

// ---------------- launch ----------------

extern "C" void kernel_launch(void* const* d_in, const int* in_sizes, int n_in,
                              void* d_out, int out_size, void* d_ws, size_t ws_size,
                              hipStream_t stream) {
    // zero per-cluster counter region (16 clusters x 128 ints)
    hipMemsetAsync(d_ws, 0, CLN * 128 * sizeof(int), stream);

    Args A;
    A.params     = (const float*)d_in[0];
    A.disp       = (const float*)d_in[1];
    A.ew         = (const float*)d_in[2];
    A.embed_b    = (const float*)d_in[3];
    A.embed_g    = (const float*)d_in[4];
    A.embed_beta = (const float*)d_in[5];
    A.sw         = (const float*)d_in[6];
    A.skip_b     = (const float*)d_in[7];
    A.gw         = (const float*)d_in[8];
    A.gates_b    = (const float*)d_in[9];
    A.inln_g     = (const float*)d_in[10];
    A.inln_b     = (const float*)d_in[11];
    A.hln_g      = (const float*)d_in[12];
    A.hln_b      = (const float*)d_in[13];
    A.sln_g      = (const float*)d_in[14];
    A.sln_b      = (const float*)d_in[15];
    A.a1w        = (const float*)d_in[16];
    A.ab1        = (const float*)d_in[17];
    A.aw2        = (const float*)d_in[18];
    A.ab2        = (const float*)d_in[19];
    A.r1w        = (const float*)d_in[20];
    A.rb1        = (const float*)d_in[21];
    A.r2w        = (const float*)d_in[22];
    A.rb2        = (const float*)d_in[23];
    A.rln_g      = (const float*)d_in[24];
    A.rln_b      = (const float*)d_in[25];
    A.o1w        = (const float*)d_in[26];
    A.ob1        = (const float*)d_in[27];
    A.oln_g      = (const float*)d_in[28];
    A.oln_b      = (const float*)d_in[29];
    A.ow2        = (const float*)d_in[30];
    A.ob2        = (const float*)d_in[31];
    A.out        = (float*)d_out;
    A.bar        = (int*)d_ws;
    A.act        = (float*)d_ws + CLN * 128;

    xlstm_kernel<<<CLN * SWG, NTH, 0, stream>>>(A);
}

// Round 13
// 22603.745 us; speedup vs baseline: 2.0162x; 2.0162x over previous
//
#include <hip/hip_runtime.h>
#include <cstdint>

#define TT 256
#define HH 256
#define LL 3
#define NTH 512
#define SWG 8          // WGs per cluster
#define CLN 32         // clusters
#define RW 4           // rows per cluster
#define LN_EPS 1e-5f
#define ACTSTRIDE 16384 // floats per cluster in d_ws act region

// ---------------- helpers ----------------

__device__ __forceinline__ float fast_sigmoid(float x) {
    return 1.f / (1.f + __expf(-x));
}
__device__ __forceinline__ float fast_tanh(float x) {
    float xc = fminf(fmaxf(x, -15.f), 15.f);
    float e = __expf(2.f * xc);
    return 1.f - 2.f / (e + 1.f);
}
__device__ __forceinline__ float relu(float x) { return fmaxf(x, 0.f); }

// LLC-coherent scalar access (lowered to global_load/store sc0 sc1).
__device__ __forceinline__ void cst(float* p, float v) {
    __hip_atomic_store(p, v, __ATOMIC_RELAXED, __HIP_MEMORY_SCOPE_AGENT);
}
__device__ __forceinline__ float cld(const float* p) {
    return __hip_atomic_load(p, __ATOMIC_RELAXED, __HIP_MEMORY_SCOPE_AGENT);
}

// Dual-row (sum, sumsq) reduction. Thread (n=tid&255, p=tid>>8) owns rows
// p and p+2. Returns (sumA, sqA, sumB, sqB). scr: 32 floats.
__device__ __forceinline__ float4 rowsum4(float s0, float q0, float s1, float q1,
                                          float* scr, int tid) {
#pragma unroll
    for (int o = 32; o > 0; o >>= 1) {
        s0 += __shfl_down(s0, o); q0 += __shfl_down(q0, o);
        s1 += __shfl_down(s1, o); q1 += __shfl_down(q1, o);
    }
    int w = tid >> 6;
    if ((tid & 63) == 0) { scr[w*4] = s0; scr[w*4+1] = q0; scr[w*4+2] = s1; scr[w*4+3] = q1; }
    __syncthreads();
    int base = (tid >> 8) * 16;
    float sA = 0, qA = 0, sB = 0, qB = 0;
#pragma unroll
    for (int i = 0; i < 4; i++) {
        sA += scr[base + i*4];     qA += scr[base + i*4 + 1];
        sB += scr[base + i*4 + 2]; qB += scr[base + i*4 + 3];
    }
    __syncthreads();
    return make_float4(sA, qA, sB, qB);
}

// Fused 8-value reduction (two dual-row LN stats in ONE tree + one barrier
// pair). Same row mapping as rowsum4. scr: 64 floats.
__device__ __forceinline__ void rowsum8(float v[8], float* scr, int tid) {
#pragma unroll
    for (int o = 32; o > 0; o >>= 1)
#pragma unroll
        for (int i = 0; i < 8; i++) v[i] += __shfl_down(v[i], o);
    int w = tid >> 6;
    if ((tid & 63) == 0)
#pragma unroll
        for (int i = 0; i < 8; i++) scr[w*8 + i] = v[i];
    __syncthreads();
    int b0 = (tid >> 8) * 4;   // waves 4p..4p+3
    float s[8] = {0,0,0,0,0,0,0,0};
#pragma unroll
    for (int k = 0; k < 4; k++)
#pragma unroll
        for (int i = 0; i < 8; i++) s[i] += scr[(b0 + k)*8 + i];
    __syncthreads();
#pragma unroll
    for (int i = 0; i < 8; i++) v[i] = s[i];
}

__device__ __forceinline__ void fma16(float4 w, float4 x,
                                      float4& a0, float4& a1, float4& a2, float4& a3) {
    a0.x = fmaf(w.x, x.x, a0.x); a0.y = fmaf(w.y, x.x, a0.y);
    a0.z = fmaf(w.z, x.x, a0.z); a0.w = fmaf(w.w, x.x, a0.w);
    a1.x = fmaf(w.x, x.y, a1.x); a1.y = fmaf(w.y, x.y, a1.y);
    a1.z = fmaf(w.z, x.y, a1.z); a1.w = fmaf(w.w, x.y, a1.w);
    a2.x = fmaf(w.x, x.z, a2.x); a2.y = fmaf(w.y, x.z, a2.y);
    a2.z = fmaf(w.z, x.z, a2.z); a2.w = fmaf(w.w, x.z, a2.w);
    a3.x = fmaf(w.x, x.w, a3.x); a3.y = fmaf(w.y, x.w, a3.y);
    a3.z = fmaf(w.z, x.w, a3.z); a3.w = fmaf(w.w, x.w, a3.w);
}

// ---------------- main kernel ----------------

struct Args {
    const float *params, *disp;
    const float *embed_b, *embed_g, *embed_beta;
    const float *skip_b;
    const float *gates_b;
    const float *inln_g, *inln_b, *hln_g, *hln_b, *sln_g, *sln_b;
    const float *ab1, *aw2, *ab2;
    const float *rb1, *rb2, *rln_g, *rln_b;
    const float *ob1, *oln_g, *oln_b, *ow2, *ob2;
    const float *gw, *a1w, *r1w, *r2w, *ew, *sw, *o1w;
    float* out;
    float* act;   // cluster activation buffers (accessed ONLY via cst/cld)
    int* bar;     // per-cluster sum counter, 128-int stride
};

__global__ __launch_bounds__(NTH) void xlstm_kernel(Args A) {
    const int tid = threadIdx.x;
    const int cid = blockIdx.x & 31;   // cluster id; members share XCD (blockIdx%8)
    const int m   = blockIdx.x >> 5;   // member 0..7
    const int n   = tid & 255;
    const int p   = tid >> 8;          // 0/1 -> rows p, p+2
    const int rA = p, rB = p + 2;

    float* gatesB = A.act + (size_t)cid * ACTSTRIDE;   // [4][1024]
    float* a1B  = gatesB + 4096;                       // [8][4] imp partials
    float* r2P  = gatesB + 4224;                       // [8][4][256] r2 partials
    int* cnt = A.bar + cid * 128;                      // cluster sum counter

    // LDS. P4 planes: [row][kg][j], plane stride padded (516/260) in float4s.
    __shared__ __align__(16) float4 P4[2064];     // 33 KB partials
    __shared__ __align__(16) float4 xnhnT[512];
    __shared__ __align__(16) float4 cT4[256];
    __shared__ __align__(16) float4 hT4[256];
    __shared__ __align__(16) float4 xT4[256];
    __shared__ __align__(16) float4 skT4[128];
    __shared__ __align__(16) float4 r1locT[64];   // member's r1 slice, [local_k][row]
    __shared__ float xtT[17 * 4];
    __shared__ float scr[64];

    float x2[2] = {0.f, 0.f};
    float h2[LL][2] = {{0.f,0.f},{0.f,0.f},{0.f,0.f}};
    float c2[LL][2] = {{0.f,0.f},{0.f,0.f},{0.f,0.f}};

    int ep = 0;
    // Sum-counter cluster barrier (proven R5).
    auto csig = [&]() {
        ep++;
        __syncthreads();   // all WG cst stores drained to LLC
        if (tid == 0)
            __hip_atomic_fetch_add(cnt, 1, __ATOMIC_RELAXED, __HIP_MEMORY_SCOPE_AGENT);
    };
    auto cwait = [&]() {
        if (tid == 0) {
            while (__hip_atomic_load(cnt, __ATOMIC_RELAXED, __HIP_MEMORY_SCOPE_AGENT) < SWG * ep)
                __builtin_amdgcn_s_sleep(4);
            asm volatile("" ::: "memory");   // compiler ordering only
        }
        __syncthreads();
    };

    if (tid < 64) {
        int k = tid >> 2, rr = tid & 3;
        xtT[(1 + k) * 4 + rr] = A.params[(RW * cid + rr) * 16 + k];
    }
    if (tid < 4) xtT[tid] = A.disp[(RW * cid + tid) * TT + 0];
    __syncthreads();

    for (int t = 0; t < TT; t++) {
        // ---- embed + skip (redundant in every member); xtT primed by prev step ----
        float e0 = A.embed_b[n], e1 = e0;
#pragma unroll 4
        for (int k = 0; k < 17; k++) {
            float w = A.ew[k * 256 + n];
            e0 = fmaf(w, xtT[k * 4 + rA], e0);
            e1 = fmaf(w, xtT[k * 4 + rB], e1);
        }
        {
            int mm = tid & 127, q = tid >> 7;
            float s = A.skip_b[mm];
#pragma unroll 4
            for (int k = 0; k < 17; k++) s = fmaf(A.sw[k * 128 + mm], xtT[k * 4 + q], s);
            ((float*)&skT4[mm])[q] = relu(s);
        }
        float4 rs = rowsum4(e0, e0 * e0, e1, e1 * e1, scr, tid);
        {
            float mu = rs.x * (1.f/HH), inv = rsqrtf(rs.y * (1.f/HH) - mu*mu + LN_EPS);
            x2[0] = relu((e0 - mu) * inv * A.embed_g[n] + A.embed_beta[n]);
            mu = rs.z * (1.f/HH); inv = rsqrtf(rs.w * (1.f/HH) - mu*mu + LN_EPS);
            x2[1] = relu((e1 - mu) * inv * A.embed_g[n] + A.embed_beta[n]);
        }

#pragma unroll 1
        for (int l = 0; l < LL; l++) {
            // ---- phase A (redundant): FUSED xn+hn LN stats, stage cT ----
            float hA = h2[l][0], hB = h2[l][1];
            {
                float v8[8] = { x2[0], x2[0]*x2[0], x2[1], x2[1]*x2[1],
                                hA, hA*hA, hB, hB*hB };
                rowsum8(v8, scr, tid);
                const float* g = A.inln_g + l*HH; const float* b = A.inln_b + l*HH;
                float mu = v8[0]*(1.f/HH), inv = rsqrtf(v8[1]*(1.f/HH) - mu*mu + LN_EPS);
                ((float*)&xnhnT[n])[rA] = (x2[0] - mu) * inv * g[n] + b[n];
                mu = v8[2]*(1.f/HH); inv = rsqrtf(v8[3]*(1.f/HH) - mu*mu + LN_EPS);
                ((float*)&xnhnT[n])[rB] = (x2[1] - mu) * inv * g[n] + b[n];
                const float* g2 = A.hln_g + l*HH; const float* b2 = A.hln_b + l*HH;
                mu = v8[4]*(1.f/HH); inv = rsqrtf(v8[5]*(1.f/HH) - mu*mu + LN_EPS);
                ((float*)&xnhnT[256 + n])[rA] = (hA - mu) * inv * g2[n] + b2[n];
                mu = v8[6]*(1.f/HH); inv = rsqrtf(v8[7]*(1.f/HH) - mu*mu + LN_EPS);
                ((float*)&xnhnT[256 + n])[rB] = (hB - mu) * inv * g2[n] + b2[n];
            }
            ((float*)&cT4[n])[rA] = c2[l][0];
            ((float*)&cT4[n])[rB] = c2[l][1];
            __syncthreads();

            // ---- MV1: gates N-slice (K=512, 32 f4-cols). KG=16, PL=516 ----
            {
                int j = tid & 31, kg = tid >> 5;
                const float4* Wq = (const float4*)A.gw + (size_t)l*512*256 + (m*32 + j);
                float4 a0={0,0,0,0}, a1v={0,0,0,0}, a2={0,0,0,0}, a3={0,0,0,0};
                int k0 = kg * 32;
#pragma unroll 8
                for (int kk = 0; kk < 32; kk++) {
                    int k = k0 + kk;
                    fma16(Wq[(size_t)k * 256], xnhnT[k], a0, a1v, a2, a3);
                }
                int b = kg*32 + j;
                P4[b] = a0; P4[516 + b] = a1v; P4[2*516 + b] = a2; P4[3*516 + b] = a3;
            }
            __syncthreads();
            if (tid < 128) {
                int j2 = tid >> 2, row = tid & 3;
                float4 s = {0,0,0,0};
#pragma unroll
                for (int kg = 0; kg < 16; kg++) {
                    float4 v = P4[row*516 + kg*32 + j2];
                    s.x += v.x; s.y += v.y; s.z += v.z; s.w += v.w;
                }
                float* d = gatesB + row*1024 + m*128 + j2*4;
                cst(d+0, s.x); cst(d+1, s.y); cst(d+2, s.z); cst(d+3, s.w);
            }
            __syncthreads();
            // ---- MV1b: a1 N-slice (K=256, 8 f4-cols). KG=32, PL=260 ----
            if (tid < 256) {
                int j = tid & 7, kg = tid >> 3;
                const float4* Wq = (const float4*)A.a1w + (size_t)l*256*64 + (m*8 + j);
                float4 a0={0,0,0,0}, a1v={0,0,0,0}, a2={0,0,0,0}, a3={0,0,0,0};
                int k0 = kg * 8;
#pragma unroll
                for (int kk = 0; kk < 8; kk++) {
                    int k = k0 + kk;
                    fma16(Wq[(size_t)k * 64], cT4[k], a0, a1v, a2, a3);
                }
                int b = kg*8 + j;
                P4[b] = a0; P4[260 + b] = a1v; P4[2*260 + b] = a2; P4[3*260 + b] = a3;
            }
            __syncthreads();
            if (tid < 32) {
                int j2 = tid >> 2, row = tid & 3;
                float4 s = {0,0,0,0};
#pragma unroll
                for (int kg = 0; kg < 32; kg++) {
                    float4 v = P4[row*260 + kg*8 + j2];
                    s.x += v.x; s.y += v.y; s.z += v.z; s.w += v.w;
                }
                const float* ab1p = A.ab1 + l*HH + m*32 + j2*4;
                const float* aw2p = A.aw2 + l*HH + m*32 + j2*4;
                float d = fast_tanh(s.x + ab1p[0]) * aw2p[0]
                        + fast_tanh(s.y + ab1p[1]) * aw2p[1]
                        + fast_tanh(s.z + ab1p[2]) * aw2p[2]
                        + fast_tanh(s.w + ab1p[3]) * aw2p[3];
                scr[tid] = d;
            }
            __syncthreads();
            if (tid < 4) {
                float s = 0.f;
#pragma unroll
                for (int j2 = 0; j2 < 8; j2++) s += scr[j2*4 + tid];
                cst(a1B + m*4 + tid, s);
            }

            // ---- B1; r1w/r2w weight prefetch issued under the wait ----
            float4 w2[8], w3[8];
            csig();
            {
                int j = tid & 15, kg = tid >> 4, k0 = kg * 8;
                const float4* Wq = (const float4*)A.r1w + (size_t)l*256*128 + (m*16 + j);
#pragma unroll
                for (int kk = 0; kk < 8; kk++) w2[kk] = Wq[(size_t)(k0 + kk) * 128];
                int j3 = tid & 63, kg3 = tid >> 6, k03 = kg3 * 8;
                const float4* Wq3 = (const float4*)A.r2w + (size_t)l*512*64
                                    + (size_t)(m*64) * 64 + j3;
#pragma unroll
                for (int kk = 0; kk < 8; kk++) w3[kk] = Wq3[(size_t)(k03 + kk) * 64];
            }
            cwait();   // B1: gates + a1 partials visible

            // ---- phase B (redundant): imp, c, h ----
            float imp0, imp1;
            {
                float sA = A.ab2[l], sB = A.ab2[l];
#pragma unroll
                for (int mm = 0; mm < SWG; mm++) {
                    sA += cld(a1B + mm*4 + rA);
                    sB += cld(a1B + mm*4 + rB);
                }
                imp0 = fast_sigmoid(sA); imp1 = fast_sigmoid(sB);
            }
            const float* gb = A.gates_b + l*1024;
            float craw0, craw1, og0, og1;
            {
                const float* go = gatesB + rA*1024;
                float ii = fast_sigmoid(cld(go + n) + gb[n]);
                float ff = fast_sigmoid(cld(go + 256 + n) + gb[256+n]);
                float gg = fast_tanh(cld(go + 512 + n) + gb[512+n]);
                og0 = fast_sigmoid(cld(go + 768 + n) + gb[768+n]);
                craw0 = (ff * c2[l][0] + ii * gg) * imp0;
            }
            {
                const float* go = gatesB + rB*1024;
                float ii = fast_sigmoid(cld(go + n) + gb[n]);
                float ff = fast_sigmoid(cld(go + 256 + n) + gb[256+n]);
                float gg = fast_tanh(cld(go + 512 + n) + gb[512+n]);
                og1 = fast_sigmoid(cld(go + 768 + n) + gb[768+n]);
                craw1 = (ff * c2[l][1] + ii * gg) * imp1;
            }
            rs = rowsum4(craw0, craw0*craw0, craw1, craw1*craw1, scr, tid);
            {
                const float* g = A.sln_g + l*HH; const float* b = A.sln_b + l*HH;
                float mu = rs.x*(1.f/HH), inv = rsqrtf(rs.y*(1.f/HH) - mu*mu + LN_EPS);
                float cn = (craw0 - mu) * inv * g[n] + b[n];
                c2[l][0] = cn; float hh = og0 * fast_tanh(cn);
                h2[l][0] = hh; ((float*)&hT4[n])[rA] = hh;
                mu = rs.z*(1.f/HH); inv = rsqrtf(rs.w*(1.f/HH) - mu*mu + LN_EPS);
                cn = (craw1 - mu) * inv * g[n] + b[n];
                c2[l][1] = cn; hh = og1 * fast_tanh(cn);
                h2[l][1] = hh; ((float*)&hT4[n])[rB] = hh;
            }
            __syncthreads();

            // ---- MV2: r1 N-slice (K=256, 16 f4-cols), weights prefetched ----
            {
                int j = tid & 15, kg = tid >> 4;
                float4 a0={0,0,0,0}, a1v={0,0,0,0}, a2={0,0,0,0}, a3={0,0,0,0};
                int k0 = kg * 8;
#pragma unroll
                for (int kk = 0; kk < 8; kk++)
                    fma16(w2[kk], hT4[k0 + kk], a0, a1v, a2, a3);
                int b = kg*16 + j;
                P4[b] = a0; P4[516 + b] = a1v; P4[2*516 + b] = a2; P4[3*516 + b] = a3;
            }
            __syncthreads();
            if (tid < 64) {
                int j2 = tid >> 2, row = tid & 3;
                float4 s = {0,0,0,0};
#pragma unroll
                for (int kg = 0; kg < 32; kg++) {
                    float4 v = P4[row*516 + kg*16 + j2];
                    s.x += v.x; s.y += v.y; s.z += v.z; s.w += v.w;
                }
                const float* rb1p = A.rb1 + l*512 + m*64 + j2*4;
                ((float*)&r1locT[j2*4 + 0])[row] = relu(s.x + rb1p[0]);
                ((float*)&r1locT[j2*4 + 1])[row] = relu(s.y + rb1p[1]);
                ((float*)&r1locT[j2*4 + 2])[row] = relu(s.z + rb1p[2]);
                ((float*)&r1locT[j2*4 + 3])[row] = relu(s.w + rb1p[3]);
            }
            __syncthreads();

            // ---- MV3: r2 K-slice (rows m*64..m*64+63), weights prefetched.
            //      Uses ONLY local r1 slice -> no barrier before it.
            {
                int j = tid & 63, kg = tid >> 6;
                float4 a0={0,0,0,0}, a1v={0,0,0,0}, a2={0,0,0,0}, a3={0,0,0,0};
                int k0 = kg * 8;
#pragma unroll
                for (int kk = 0; kk < 8; kk++) {
                    int lk = k0 + kk;
                    fma16(w3[kk], r1locT[lk], a0, a1v, a2, a3);
                }
                int b = kg*64 + j;
                P4[b] = a0; P4[516 + b] = a1v; P4[2*516 + b] = a2; P4[3*516 + b] = a3;
            }
            __syncthreads();
            {
                int j2 = tid >> 2, row = tid & 3;
                if (tid < 256) {
                    float4 s = {0,0,0,0};
#pragma unroll
                    for (int kg = 0; kg < 8; kg++) {
                        float4 v = P4[row*516 + kg*64 + j2];
                        s.x += v.x; s.y += v.y; s.z += v.z; s.w += v.w;
                    }
                    float* d = r2P + m*1024 + row*256 + j2*4;
                    cst(d+0, s.x); cst(d+1, s.y); cst(d+2, s.z); cst(d+3, s.w);
                }
            }
            csig(); cwait();   // B2: r2 partials visible

            // ---- phase C (redundant): x = LN(sum r2 partials + rb2 + h) + res ----
            const float* rb2p = A.rb2 + l*HH;
            float s0 = rb2p[n] + h2[l][0];
            float s1 = rb2p[n] + h2[l][1];
#pragma unroll
            for (int mm = 0; mm < SWG; mm++) {
                s0 += cld(r2P + mm*1024 + rA*256 + n);
                s1 += cld(r2P + mm*1024 + rB*256 + n);
            }
            rs = rowsum4(s0, s0*s0, s1, s1*s1, scr, tid);
            {
                const float* g = A.rln_g + l*HH; const float* b = A.rln_b + l*HH;
                float mu = rs.x*(1.f/HH), inv = rsqrtf(rs.y*(1.f/HH) - mu*mu + LN_EPS);
                x2[0] = (s0 - mu) * inv * g[n] + b[n] + x2[0];
                mu = rs.z*(1.f/HH); inv = rsqrtf(rs.w*(1.f/HH) - mu*mu + LN_EPS);
                x2[1] = (s1 - mu) * inv * g[n] + b[n] + x2[1];
            }
        }   // layers

        // ---- head: ROTATING OWNER (m == t&7), barrier-free. The head is
        // WG-local in this structure (own LDS copies of x/skip, own out
        // column) -- proven by R5's fully-redundant version. Non-owners skip
        // ~384 FMA/thread + the 196KB o1w stream and run ahead into step
        // t+1; the owner's head hides under their lead before the next B1.
        ((float*)&xT4[n])[rA] = x2[0];
        ((float*)&xT4[n])[rB] = x2[1];
        if (tid < 4 && t < TT - 1)
            xtT[tid] = A.disp[(RW * cid + tid) * TT + t + 1];   // prime next step
        __syncthreads();
        if (m == (t & 7)) {
            {
                int j = tid & 31, z = tid >> 5;   // z 0..15
                int row = z & 3, kg = z >> 2;     // kg 0..3 x 96 k
                const float4* W4 = (const float4*)A.o1w;
                float4 a4 = {0,0,0,0};
                int k0 = kg * 96;
#pragma unroll 8
                for (int kk = 0; kk < 96; kk++) {
                    int k = k0 + kk;
                    float xv = (k < 256) ? ((const float*)&xT4[k])[row]
                                         : ((const float*)&skT4[k - 256])[row];
                    float4 w = W4[(size_t)k * 32 + j];
                    a4.x = fmaf(w.x, xv, a4.x); a4.y = fmaf(w.y, xv, a4.y);
                    a4.z = fmaf(w.z, xv, a4.z); a4.w = fmaf(w.w, xv, a4.w);
                }
                P4[z * 33 + j] = a4;
            }
            __syncthreads();
            if (tid < 128) {
                int j = tid & 31, row = tid >> 5;
                float4 v = {0,0,0,0};
#pragma unroll
                for (int kg = 0; kg < 4; kg++) {
                    float4 pv = P4[(kg * 4 + row) * 33 + j];
                    v.x += pv.x; v.y += pv.y; v.z += pv.z; v.w += pv.w;
                }
                float4 b1 = ((const float4*)A.ob1)[j];
                v.x += b1.x; v.y += b1.y; v.z += b1.z; v.w += b1.w;
                float s = v.x + v.y + v.z + v.w;
                float q = v.x*v.x + v.y*v.y + v.z*v.z + v.w*v.w;
#pragma unroll
                for (int o = 16; o > 0; o >>= 1) { s += __shfl_down(s, o); q += __shfl_down(q, o); }
                s = __shfl(s, tid & 32);   // broadcast from lane 0 of each 32-half
                q = __shfl(q, tid & 32);
                float mu = s * (1.f/128.f);
                float inv = rsqrtf(q * (1.f/128.f) - mu*mu + LN_EPS);
                float4 g4 = ((const float4*)A.oln_g)[j];
                float4 be4 = ((const float4*)A.oln_b)[j];
                float4 w24 = ((const float4*)A.ow2)[j];
                float part = relu((v.x - mu) * inv * g4.x + be4.x) * w24.x
                           + relu((v.y - mu) * inv * g4.y + be4.y) * w24.y
                           + relu((v.z - mu) * inv * g4.z + be4.z) * w24.z
                           + relu((v.w - mu) * inv * g4.w + be4.w) * w24.w;
#pragma unroll
                for (int o = 16; o > 0; o >>= 1) part += __shfl_down(part, o);
                if ((tid & 31) == 0)
                    A.out[(RW*cid + row) * TT + t] = part + A.ob2[0];
            }
        }
        __syncthreads();   // protect LDS (xT4/skT4/P4) for next step
    }
}

// ---------------- launch ----------------

extern "C" void kernel_launch(void* const* d_in, const int* in_sizes, int n_in,
                              void* d_out, int out_size, void* d_ws, size_t ws_size,
                              hipStream_t stream) {
    // zero per-cluster counter region (32 clusters x 128 ints)
    hipMemsetAsync(d_ws, 0, CLN * 128 * sizeof(int), stream);

    Args A;
    A.params     = (const float*)d_in[0];
    A.disp       = (const float*)d_in[1];
    A.ew         = (const float*)d_in[2];
    A.embed_b    = (const float*)d_in[3];
    A.embed_g    = (const float*)d_in[4];
    A.embed_beta = (const float*)d_in[5];
    A.sw         = (const float*)d_in[6];
    A.skip_b     = (const float*)d_in[7];
    A.gw         = (const float*)d_in[8];
    A.gates_b    = (const float*)d_in[9];
    A.inln_g     = (const float*)d_in[10];
    A.inln_b     = (const float*)d_in[11];
    A.hln_g      = (const float*)d_in[12];
    A.hln_b      = (const float*)d_in[13];
    A.sln_g      = (const float*)d_in[14];
    A.sln_b      = (const float*)d_in[15];
    A.a1w        = (const float*)d_in[16];
    A.ab1        = (const float*)d_in[17];
    A.aw2        = (const float*)d_in[18];
    A.ab2        = (const float*)d_in[19];
    A.r1w        = (const float*)d_in[20];
    A.rb1        = (const float*)d_in[21];
    A.r2w        = (const float*)d_in[22];
    A.rb2        = (const float*)d_in[23];
    A.rln_g      = (const float*)d_in[24];
    A.rln_b      = (const float*)d_in[25];
    A.o1w        = (const float*)d_in[26];
    A.ob1        = (const float*)d_in[27];
    A.oln_g      = (const float*)d_in[28];
    A.oln_b      = (const float*)d_in[29];
    A.ow2        = (const float*)d_in[30];
    A.ob2        = (const float*)d_in[31];
    A.out        = (float*)d_out;
    A.bar        = (int*)d_ws;
    A.act        = (float*)d_ws + CLN * 128;

    xlstm_kernel<<<CLN * SWG, NTH, 0, stream>>>(A);
}